// Round 5
// baseline (457.842 us; speedup 1.0000x reference)
//
#include <hip/hip_runtime.h>
#include <hip/hip_bf16.h>
#include <math.h>

// Problem: B=2, S=1024, D_MODEL=3072, HEADS=24, HEAD_DIM=128
#define B_   2
#define S_   1024
#define DM_  3072
#define H_   24
#define HD_  128
#define BH_  (B_*H_)          // 48
#define KDIM 3072             // K of both GEMMs
#define QSCALE 0.08838834764831845f   // 1/sqrt(128)

typedef __attribute__((ext_vector_type(8))) short short8;
typedef __attribute__((ext_vector_type(4))) float f32x4;

__device__ __forceinline__ unsigned short f2bf(float f) {
    union { float f; unsigned u; } v; v.f = f;
    unsigned r = v.u + 0x7fffu + ((v.u >> 16) & 1u);   // RNE
    return (unsigned short)(r >> 16);
}

// async 16B global -> LDS (wave-uniform lds base; HW scatters lane*16)
#define GLD_LDS16(gptr, ldsptr)                                                            \
    __builtin_amdgcn_global_load_lds(                                                      \
        (const __attribute__((address_space(1))) unsigned int*)(gptr),                     \
        (__attribute__((address_space(3))) unsigned int*)(ldsptr), 16, 0, 0)

// ---------------- merged fp32->bf16 conversion + rope table ----------------
// segments (in float4 units): hs(1572864) | Wq | Wk | Wv (2359296 ea) | Wo | rope(32768)
#define SEG0 1572864
#define SEGW 2359296
#define SB1  (SEG0 + SEGW)        // 3932160
#define SB2  (SB1 + SEGW)         // 6291456
#define SB3  (SB2 + SEGW)         // 8650752
#define SB4  (SB3 + SEGW)         // 11010048
#define SB5  (SB4 + 32768)        // 11042816
#define CVT_BLOCKS 43136          // SB5/256

__global__ __launch_bounds__(256) void cvt_all(const float* __restrict__ hs,
                                               const float* __restrict__ Wq,
                                               const float* __restrict__ Wk,
                                               const float* __restrict__ Wv,
                                               const float* __restrict__ Wo,
                                               const float* __restrict__ freqs,
                                               unsigned short* __restrict__ Xb,
                                               unsigned short* __restrict__ Wqkvb,
                                               unsigned short* __restrict__ Wob,
                                               float2* __restrict__ tab) {
    int i = blockIdx.x * 256 + threadIdx.x;
    const float* src;
    unsigned short* dst;
    int j;
    if (i < SEG0)      { src = hs; dst = Xb;              j = i; }
    else if (i < SB1)  { src = Wq; dst = Wqkvb;           j = i - SEG0; }
    else if (i < SB2)  { src = Wk; dst = Wqkvb + 9437184; j = i - SB1; }
    else if (i < SB3)  { src = Wv; dst = Wqkvb + 18874368; j = i - SB2; }
    else if (i < SB4)  { src = Wo; dst = Wob;             j = i - SB3; }
    else {
        j = i - SB4;               // rope: 32768 float4 of freqs
        float4 f = ((const float4*)freqs)[j];
        float4 lo = make_float4(cosf(f.x), sinf(f.x), cosf(f.y), sinf(f.y));
        float4 hi = make_float4(cosf(f.z), sinf(f.z), cosf(f.w), sinf(f.w));
        ((float4*)tab)[2 * j]     = lo;
        ((float4*)tab)[2 * j + 1] = hi;
        return;
    }
    float4 v = ((const float4*)src)[j];
    ushort4 o;
    o.x = f2bf(v.x); o.y = f2bf(v.y); o.z = f2bf(v.z); o.w = f2bf(v.w);
    ((ushort4*)dst)[j] = o;
}

// ---------------- fused QKV GEMM + RMSNorm + RoPE ----------------
// C[M,N]=A[M,K]*B[N,K]^T, 128x128 tile, BK=64, 4 waves (64x64 each).
// grid (16 my, 72 nx): my fastest so the 16 blocks sharing a B-panel are
// temporally adjacent (L2/LLC reuse); A stays fully hot in LLC.
// B rows PERMUTED at staging: wave p=w&1 holds cols p=0:{0-31,64-95},
// p=1:{32-63,96-127} -> each RoPE pair (d,d+64) lives in one lane.
__global__ __launch_bounds__(256) void gemm_qkv(const unsigned short* __restrict__ A,
                                                const unsigned short* __restrict__ Bm,
                                                const float2* __restrict__ rtab,
                                                const float* __restrict__ nqw,
                                                const float* __restrict__ nkw,
                                                unsigned short* __restrict__ Qb,
                                                unsigned short* __restrict__ Kb,
                                                unsigned short* __restrict__ Vtb) {
    __shared__ __align__(16) unsigned short As[128 * 64];
    __shared__ __align__(16) unsigned short Bs[128 * 64];
    __shared__ float pse[4][64];
    const int t = threadIdx.x;
    const int bx = blockIdx.y;                      // 0..71 (n-panel)
    const int m0 = blockIdx.x * 128, n0 = bx * 128;
    const int w = t >> 6, lane = t & 63, quad = lane >> 4, ln = lane & 15;
    const int wm = (w >> 1) * 64;
    const int p = w & 1;
    const int dj0 = p ? 32 : 0;
    const int rl = lane >> 3;             // row within 8-row staging group
    const int gc = (lane & 7) ^ rl;       // swizzled global chunk this lane fetches
    const int cs = ln & 7;                // read-side swizzle key
    const int woff = (w == 1) ? 32 : (w == 2) ? -32 : 0;   // B-row permutation

    f32x4 acc[4][4];
#pragma unroll
    for (int i = 0; i < 4; ++i)
#pragma unroll
        for (int j = 0; j < 4; ++j) acc[i][j] = (f32x4){0.f, 0.f, 0.f, 0.f};

    const unsigned short* ga = &A[(long long)(m0 + w * 32 + rl) * KDIM + gc * 8];
    const unsigned short* gb = &Bm[(long long)(n0 + w * 32 + woff + rl) * KDIM + gc * 8];

    for (int kt = 0; kt < KDIM / 64; ++kt) {
#pragma unroll
        for (int c = 0; c < 4; ++c) {
            const int r0 = w * 32 + c * 8;
            GLD_LDS16(ga + (long long)(c * 8) * KDIM, &As[r0 * 64]);
            GLD_LDS16(gb + (long long)(c * 8) * KDIM, &Bs[r0 * 64]);
        }
        ga += 64; gb += 64;
        __syncthreads();
#pragma unroll
        for (int ks = 0; ks < 2; ++ks) {
            short8 a[4], b[4];
#pragma unroll
            for (int i = 0; i < 4; ++i) {
                int row = wm + i * 16 + ln;
                a[i] = *(const short8*)&As[row * 64 + (((ks * 4 + quad) ^ cs) << 3)];
            }
#pragma unroll
            for (int j = 0; j < 4; ++j) {
                int row = p * 64 + j * 16 + ln;
                b[j] = *(const short8*)&Bs[row * 64 + (((ks * 4 + quad) ^ cs) << 3)];
            }
#pragma unroll
            for (int i = 0; i < 4; ++i)
#pragma unroll
                for (int j = 0; j < 4; ++j)
                    acc[i][j] = __builtin_amdgcn_mfma_f32_16x16x32_bf16(a[i], b[j], acc[i][j], 0, 0, 0);
        }
        __syncthreads();
    }

    // epilogue: row = m0+wm+i*16+quad*4+reg, col = n0+dj0+(j&1)*16+(j>>1)*64+ln
    const int region = bx / 24;        // 0=Q, 1=K, 2=V (block-uniform)
    const int h = bx % 24;
    if (region < 2) {
#pragma unroll
        for (int i = 0; i < 4; ++i)
#pragma unroll
            for (int reg = 0; reg < 4; ++reg) {
                float s = 0.f;
#pragma unroll
                for (int j = 0; j < 4; ++j) { float v = acc[i][j][reg]; s += v * v; }
#pragma unroll
                for (int off = 8; off; off >>= 1) s += __shfl_xor(s, off, 16);
                if (ln == 0) pse[w][i * 16 + quad * 4 + reg] = s;
            }
        __syncthreads();
        const float* nw = region ? nkw : nqw;
        unsigned short* outp = region ? Kb : Qb;
        const float scl = region ? 1.f : QSCALE;
        const float nw0  = nw[dj0 + ln],      nw1  = nw[dj0 + 16 + ln];
        const float nw64 = nw[dj0 + 64 + ln], nw80 = nw[dj0 + 80 + ln];
#pragma unroll
        for (int i = 0; i < 4; ++i)
#pragma unroll
            for (int reg = 0; reg < 4; ++reg) {
                const int idx = i * 16 + quad * 4 + reg;
                const float tot = pse[w][idx] + pse[w ^ 1][idx];
                const float rr = rsqrtf(tot * (1.f / 128.f) + 1e-6f);
                const int row = m0 + wm + idx;
                const int b = row >> 10, s = row & 1023;
                const long long ob = ((long long)(b * H_ + h) * S_ + s) * HD_;
                {
                    const int d1 = dj0 + ln;
                    float y1 = acc[i][0][reg] * rr * nw0;
                    float y2 = acc[i][2][reg] * rr * nw64;
                    float2 c1 = rtab[s * HD_ + d1], c2 = rtab[s * HD_ + d1 + 64];
                    outp[ob + d1]      = f2bf((y1 * c1.x - y2 * c1.y) * scl);
                    outp[ob + d1 + 64] = f2bf((y2 * c2.x + y1 * c2.y) * scl);
                }
                {
                    const int d1 = dj0 + 16 + ln;
                    float y1 = acc[i][1][reg] * rr * nw1;
                    float y2 = acc[i][3][reg] * rr * nw80;
                    float2 c1 = rtab[s * HD_ + d1], c2 = rtab[s * HD_ + d1 + 64];
                    outp[ob + d1]      = f2bf((y1 * c1.x - y2 * c1.y) * scl);
                    outp[ob + d1 + 64] = f2bf((y2 * c2.x + y1 * c2.y) * scl);
                }
            }
    } else {
        // V: store transposed (B,H,D,S)
#pragma unroll
        for (int i = 0; i < 4; ++i)
#pragma unroll
            for (int reg = 0; reg < 4; ++reg) {
                const int row = m0 + wm + i * 16 + quad * 4 + reg;
                const int b = row >> 10, s = row & 1023;
                const long long vb = (long long)(b * H_ + h) * HD_;
#pragma unroll
                for (int j = 0; j < 4; ++j) {
                    const int d = dj0 + (j & 1) * 16 + (j >> 1) * 64 + ln;
                    Vtb[(vb + d) * S_ + s] = f2bf(acc[i][j][reg]);
                }
            }
    }
}

// ---------------- output projection GEMM ----------------
// C[M,N] = A[M,K]*B[N,K]^T, fp32 out. 64x128 tile, BK=64, 4 waves (32x64 each).
// 768 blocks (3/CU), 24.6 KB LDS, low VGPR -> high overlap for latency-bound loop.
// grid (32 my, 24 nx): my fastest so B-panel sharers are adjacent.
__global__ __launch_bounds__(256) void gemm_out(const unsigned short* __restrict__ A,
                                                const unsigned short* __restrict__ Bm,
                                                float* __restrict__ C, int Ndim) {
    __shared__ __align__(16) unsigned short As[64 * 64];
    __shared__ __align__(16) unsigned short Bs[128 * 64];
    const int t = threadIdx.x;
    const int m0 = blockIdx.x * 64, n0 = blockIdx.y * 128;
    const int w = t >> 6, lane = t & 63, quad = lane >> 4, ln = lane & 15;
    const int wm = (w >> 1) * 32, wn = (w & 1) * 64;
    const int rl = lane >> 3;
    const int gc = (lane & 7) ^ rl;
    const int cs = ln & 7;

    f32x4 acc[2][4];
#pragma unroll
    for (int i = 0; i < 2; ++i)
#pragma unroll
        for (int j = 0; j < 4; ++j) acc[i][j] = (f32x4){0.f, 0.f, 0.f, 0.f};

    const unsigned short* ga = &A[(long long)(m0 + w * 16 + rl) * KDIM + gc * 8];
    const unsigned short* gb = &Bm[(long long)(n0 + w * 32 + rl) * KDIM + gc * 8];

    for (int kt = 0; kt < KDIM / 64; ++kt) {
#pragma unroll
        for (int c = 0; c < 2; ++c)
            GLD_LDS16(ga + (long long)(c * 8) * KDIM, &As[(w * 16 + c * 8) * 64]);
#pragma unroll
        for (int c = 0; c < 4; ++c)
            GLD_LDS16(gb + (long long)(c * 8) * KDIM, &Bs[(w * 32 + c * 8) * 64]);
        ga += 64; gb += 64;
        __syncthreads();
#pragma unroll
        for (int ks = 0; ks < 2; ++ks) {
            short8 a[2], b[4];
#pragma unroll
            for (int i = 0; i < 2; ++i) {
                int row = wm + i * 16 + ln;
                a[i] = *(const short8*)&As[row * 64 + (((ks * 4 + quad) ^ cs) << 3)];
            }
#pragma unroll
            for (int j = 0; j < 4; ++j) {
                int row = wn + j * 16 + ln;
                b[j] = *(const short8*)&Bs[row * 64 + (((ks * 4 + quad) ^ cs) << 3)];
            }
#pragma unroll
            for (int i = 0; i < 2; ++i)
#pragma unroll
                for (int j = 0; j < 4; ++j)
                    acc[i][j] = __builtin_amdgcn_mfma_f32_16x16x32_bf16(a[i], b[j], acc[i][j], 0, 0, 0);
        }
        __syncthreads();
    }
#pragma unroll
    for (int i = 0; i < 2; ++i)
#pragma unroll
        for (int reg = 0; reg < 4; ++reg) {
            int row = m0 + wm + i * 16 + quad * 4 + reg;
            float* crow = C + (long long)row * Ndim + n0 + wn + ln;
#pragma unroll
            for (int j = 0; j < 4; ++j) crow[j * 16] = acc[i][j][reg];
        }
}

// ---------------- Flash attention (no-max softmax; scores bounded by ~11.32)
// grid (16 qt, 48 bh): qt fastest so the 16 blocks sharing one head's K/V
// are temporally adjacent. 4 waves/block, each wave owns 16 Q rows.
__global__ __launch_bounds__(256) void attn(const unsigned short* __restrict__ Qb,
                                            const unsigned short* __restrict__ Kb,
                                            const unsigned short* __restrict__ Vtb,
                                            unsigned short* __restrict__ Ob) {
    __shared__ __align__(16) unsigned short Ks[64 * 128];   // swizzled: slot s of row r = chunk s^(r&15)
    __shared__ __align__(16) unsigned short Vts[128 * 64];  // swizzled: slot s of row r = chunk s^(r&7)
    __shared__ __align__(16) unsigned short Ps[4][16][72];  // per-wave P 16x64 (+8 pad)
    const int qt = blockIdx.x, bh = blockIdx.y;
    const int t = threadIdx.x, w = t >> 6, lane = t & 63, quad = lane >> 4, ln = lane & 15;
    const int b = bh / H_, h = bh - b * H_;

    short8 qfrag[4];
    const long long qbase = ((long long)bh * S_ + qt * 64 + w * 16 + ln) * HD_;
#pragma unroll
    for (int ks = 0; ks < 4; ++ks)
        qfrag[ks] = *(const short8*)&Qb[qbase + ks * 32 + quad * 8];

    f32x4 o[8];
#pragma unroll
    for (int n = 0; n < 8; ++n) o[n] = (f32x4){0.f, 0.f, 0.f, 0.f};
    float l_run[4] = {0.f, 0.f, 0.f, 0.f};

    const int krow_l = lane >> 4, ksl = lane & 15;        // K staging: sub-row, slot
    const int vrow_l = lane >> 3, vsl = lane & 7;         // V staging: sub-row, slot

    for (int kt = 0; kt < S_ / 64; ++kt) {
        __syncthreads();
#pragma unroll
        for (int c = 0; c < 4; ++c) {
            {   // K tile: rows c*16+w*4 .. +3
                const int r = c * 16 + w * 4 + krow_l;
                const int gcn = ksl ^ (r & 15);
                GLD_LDS16(&Kb[((long long)bh * S_ + kt * 64 + r) * HD_ + gcn * 8],
                          &Ks[(c * 16 + w * 4) * 128]);
            }
            {   // V tile: rows c*32+w*8 .. +7  (row = d, cols = 64 keys)
                const int r = c * 32 + w * 8 + vrow_l;
                const int gcn = vsl ^ (r & 7);
                GLD_LDS16(&Vtb[((long long)bh * HD_ + r) * S_ + kt * 64 + gcn * 8],
                          &Vts[(c * 32 + w * 8) * 64]);
            }
        }
        __syncthreads();
        // S = Q K^T  (4 subtiles of 16 keys)
        f32x4 sj[4];
#pragma unroll
        for (int j = 0; j < 4; ++j) {
            f32x4 sa = (f32x4){0.f, 0.f, 0.f, 0.f};
#pragma unroll
            for (int ks = 0; ks < 4; ++ks) {
                const int row = j * 16 + ln;
                const int slot = (ks * 4 + quad) ^ (row & 15);
                short8 bb = *(const short8*)&Ks[row * 128 + slot * 8];
                sa = __builtin_amdgcn_mfma_f32_16x16x32_bf16(qfrag[ks], bb, sa, 0, 0, 0);
            }
            sj[j] = sa;
        }
        // softmax without max-subtraction (scores bounded); accumulate l
#pragma unroll
        for (int r = 0; r < 4; ++r) {
            float sum = 0.f;
#pragma unroll
            for (int j = 0; j < 4; ++j) {
                float p = __expf(sj[j][r]);
                sj[j][r] = p;
                sum += p;
            }
#pragma unroll
            for (int off = 8; off; off >>= 1) sum += __shfl_xor(sum, off, 16);
            l_run[r] += sum;
        }
        // P: C-layout -> LDS -> A-layout
#pragma unroll
        for (int j = 0; j < 4; ++j)
#pragma unroll
            for (int r = 0; r < 4; ++r)
                Ps[w][quad * 4 + r][j * 16 + ln] = f2bf(sj[j][r]);
        __asm__ volatile("s_waitcnt lgkmcnt(0)" ::: "memory");
        // O += P V
#pragma unroll
        for (int ks = 0; ks < 2; ++ks) {
            short8 pf = *(const short8*)&Ps[w][ln][ks * 32 + quad * 8];
#pragma unroll
            for (int n = 0; n < 8; ++n) {
                const int row = n * 16 + ln;
                const int slot = (ks * 4 + quad) ^ (row & 7);
                short8 vf = *(const short8*)&Vts[row * 64 + slot * 8];
                o[n] = __builtin_amdgcn_mfma_f32_16x16x32_bf16(pf, vf, o[n], 0, 0, 0);
            }
        }
    }
    float inv[4];
#pragma unroll
    for (int r = 0; r < 4; ++r) inv[r] = 1.f / l_run[r];
    const int row_s = qt * 64 + w * 16 + quad * 4;
#pragma unroll
    for (int n = 0; n < 8; ++n)
#pragma unroll
        for (int r = 0; r < 4; ++r) {
            long long off = ((long long)b * S_ + row_s + r) * DM_ + h * HD_ + n * 16 + ln;
            Ob[off] = f2bf(o[n][r] * inv[r]);
        }
}

// ---------------- host side ----------------
extern "C" void kernel_launch(void* const* d_in, const int* in_sizes, int n_in,
                              void* d_out, int out_size, void* d_ws, size_t ws_size,
                              hipStream_t stream) {
    const float* hs    = (const float*)d_in[0];
    const float* freqs = (const float*)d_in[1];
    const float* Wq    = (const float*)d_in[2];
    const float* Wk    = (const float*)d_in[3];
    const float* Wv    = (const float*)d_in[4];
    const float* Wo    = (const float*)d_in[5];
    const float* nqw   = (const float*)d_in[6];
    const float* nkw   = (const float*)d_in[7];
    float* out = (float*)d_out;

    char* ws = (char*)d_ws;
    unsigned short* Xb    = (unsigned short*)(ws);                   // 12,582,912
    unsigned short* Wqkvb = (unsigned short*)(ws + 12582912LL);      // 56,623,104 (Wq|Wk|Wv)
    unsigned short* Wob   = (unsigned short*)(ws + 69206016LL);      // 18,874,368
    unsigned short* Qb    = (unsigned short*)(ws + 88080384LL);      // 12,582,912 (B,H,S,D)
    unsigned short* Kb    = (unsigned short*)(ws + 100663296LL);     // 12,582,912 (B,H,S,D)
    unsigned short* Vtb   = (unsigned short*)(ws + 113246208LL);     // 12,582,912 (B,H,D,S)
    unsigned short* Ob    = (unsigned short*)(ws + 125829120LL);     // 12,582,912 (B,S,H*D)
    float2*         rtab  = (float2*)        (ws + 138412032LL);     // 1,048,576
    // total: 139,460,608 bytes

    // 1. all conversions + rope table in one launch
    cvt_all<<<CVT_BLOCKS, 256, 0, stream>>>(hs, Wq, Wk, Wv, Wo, freqs,
                                            Xb, Wqkvb, Wob, rtab);
    // 2. fused QKV projection + RMSNorm + RoPE (grid: my fast for B-panel reuse)
    gemm_qkv<<<dim3(16, 72), 256, 0, stream>>>(Xb, Wqkvb, rtab, nqw, nkw, Qb, Kb, Vtb);
    // 3. flash attention (grid: qt fast for K/V reuse)
    attn<<<dim3(16, BH_), 256, 0, stream>>>(Qb, Kb, Vtb, Ob);
    // 4. output projection -> d_out fp32 (64x128 tiles, 768 blocks)
    gemm_out<<<dim3(32, 24), 256, 0, stream>>>(Ob, Wob, out, DM_);
}